// Round 2
// baseline (41.767 us; speedup 1.0000x reference)
//
#include <hip/hip_runtime.h>

// Segment-mean over SORTED batch_ids.
// Grid = G * S blocks: block (g, s) computes output columns [s*D/S, (s+1)*D/S)
// of graph g. Column-splitting gives 2048 blocks (8/CU, full 32-wave occupancy,
// ~4x better load balance than 1 block/graph) with NO cross-block combine:
// every block owns a disjoint slice of d_out.

#define SLICES 4

__global__ __launch_bounds__(256) void segmean_kernel(
    const float* __restrict__ x,
    const int*   __restrict__ ids,
    float*       __restrict__ out,
    int N, int D)
{
    const int bid = (int)blockIdx.x;
    const int g   = bid >> 2;          // graph id   (SLICES == 4)
    const int s   = bid & 3;           // column slice

    // Two interleaved binary searches (independent dependency chains run
    // concurrently): start = lower_bound(ids, g), end = lower_bound(ids, g+1).
    int lo0 = 0, hi0 = N, lo1 = 0, hi1 = N;
    while ((lo0 < hi0) | (lo1 < hi1)) {
        if (lo0 < hi0) {
            const int m = (lo0 + hi0) >> 1;
            if (ids[m] <  g) lo0 = m + 1; else hi0 = m;
        }
        if (lo1 < hi1) {
            const int m = (lo1 + hi1) >> 1;
            if (ids[m] <= g) lo1 = m + 1; else hi1 = m;
        }
    }
    const int start = lo0;
    const int end   = lo1;
    const int count = end - start;

    const int Dslice = D >> 2;                  // 64 floats per slice
    const int tpr    = Dslice >> 2;             // 16 lanes cover one row-slice (float4)
    const int rpi    = (int)blockDim.x / tpr;   // 16 rows per block-iteration
    const int t      = (int)threadIdx.x;
    const int rowoff = t / tpr;                 // lane's row within the iter group
    const int col    = s * Dslice + (t % tpr) * 4;

    float4 acc = make_float4(0.f, 0.f, 0.f, 0.f);
    #pragma unroll 2
    for (int r = start + rowoff; r < end; r += rpi) {
        const float4 v = *reinterpret_cast<const float4*>(x + (size_t)r * (size_t)D + col);
        acc.x += v.x; acc.y += v.y; acc.z += v.z; acc.w += v.w;
    }

    // Reduce across the 16 rowoff groups.
    // Within a wave, rowoff spans lane/16 (4 groups): butterfly over lane bits 4,5.
    acc.x += __shfl_xor(acc.x, 16); acc.y += __shfl_xor(acc.y, 16);
    acc.z += __shfl_xor(acc.z, 16); acc.w += __shfl_xor(acc.w, 16);
    acc.x += __shfl_xor(acc.x, 32); acc.y += __shfl_xor(acc.y, 32);
    acc.z += __shfl_xor(acc.z, 32); acc.w += __shfl_xor(acc.w, 32);

    // Cross-wave (4 waves) via 1 KiB LDS.
    __shared__ float4 sdata[4][16];
    const int wave = t >> 6;
    const int lane = t & 63;
    if (lane < 16) sdata[wave][lane] = acc;
    __syncthreads();

    if (t < tpr) {
        const float4 a = sdata[0][t];
        const float4 b = sdata[1][t];
        const float4 c = sdata[2][t];
        const float4 d = sdata[3][t];
        const float inv = 1.0f / (float)count;  // empty segments: P ~ e^-390, NaN matches ref
        float4 o;
        o.x = ((a.x + b.x) + (c.x + d.x)) * inv;
        o.y = ((a.y + b.y) + (c.y + d.y)) * inv;
        o.z = ((a.z + b.z) + (c.z + d.z)) * inv;
        o.w = ((a.w + b.w) + (c.w + d.w)) * inv;
        *reinterpret_cast<float4*>(out + (size_t)g * (size_t)D + col) = o;
    }
}

extern "C" void kernel_launch(void* const* d_in, const int* in_sizes, int n_in,
                              void* d_out, int out_size, void* d_ws, size_t ws_size,
                              hipStream_t stream) {
    const float* x   = (const float*)d_in[0];
    const int*   ids = (const int*)d_in[1];
    float*       out = (float*)d_out;

    const int N = in_sizes[1];            // 200000 rows
    const int D = in_sizes[0] / N;        // 256 features
    const int G = out_size / D;           // 512 graphs

    dim3 grid(G * SLICES), block(256);
    segmean_kernel<<<grid, block, 0, stream>>>(x, ids, out, N, D);
}